// Round 6
// baseline (229.787 us; speedup 1.0000x reference)
//
#include <hip/hip_runtime.h>
#include <hip/hip_bf16.h>
#include <math.h>

#define S_LEN 4096
#define EMB   1024
#define HEAD  128

typedef short bf16x8 __attribute__((ext_vector_type(8)));
typedef short s16x4  __attribute__((ext_vector_type(4)));
typedef float f32x4  __attribute__((ext_vector_type(4)));

static __device__ __forceinline__ short f2bf(float x){
  unsigned u = __builtin_bit_cast(unsigned, x);
  u += 0x7fffu + ((u >> 16) & 1u);
  return (short)(u >> 16);
}
static __device__ __forceinline__ f32x4 mfma16(bf16x8 a, bf16x8 b, f32x4 c){
  return __builtin_amdgcn_mfma_f32_16x16x32_bf16(a, b, c, 0, 0, 0);
}
static __device__ __forceinline__ void gload16(const void* g, void* l){
  __builtin_amdgcn_global_load_lds((const __attribute__((address_space(1))) unsigned*)g,
                                   (__attribute__((address_space(3))) unsigned*)l, 16, 0, 0);
}

// ---------------------------------------------------------------------------
// Kernel 0: WT_cat[384][1024] bf16 (transposed, Q pre-scaled by 1/sqrt(128)),
// bias_cat[384] f32.
// ---------------------------------------------------------------------------
__global__ void prep_w(const float* __restrict__ Wq, const float* __restrict__ bq,
                       const float* __restrict__ Wk, const float* __restrict__ bk,
                       const float* __restrict__ Wv, const float* __restrict__ bv,
                       short* __restrict__ WT, float* __restrict__ bias){
  int idx = blockIdx.x * 256 + threadIdx.x;
  int nc  = idx >> 10;
  int k   = idx & 1023;
  int mat = nc >> 7;
  int n   = nc & 127;
  const float* W = (mat == 0) ? Wq : (mat == 1) ? Wk : Wv;
  float s = (mat == 0) ? 0.08838834764831845f : 1.0f;
  WT[idx] = f2bf(W[k * HEAD + n] * s);
  if (idx < 384){
    int m2 = idx >> 7, n2 = idx & 127;
    const float* bsrc = (m2 == 0) ? bq : (m2 == 1) ? bk : bv;
    float s2 = (m2 == 0) ? 0.08838834764831845f : 1.0f;
    bias[idx] = bsrc[n2] * s2;
  }
}

// ---------------------------------------------------------------------------
// Kernel 1: fused QKV projection (verified round-4/5 structure, unchanged).
// ---------------------------------------------------------------------------
__global__ __launch_bounds__(512) void qkv_proj(const float* __restrict__ x,
    const short* __restrict__ WT, const float* __restrict__ bias,
    short* __restrict__ Qo, short* __restrict__ Ko, short* __restrict__ VTo){
  __shared__ __align__(16) short Wl[2][24576];   // 48KB each
  __shared__ __align__(16) float Xl[2][4096];    // 16KB each
  __shared__ __align__(16) short Vb[128 * 72];   // 18KB bounce

  const int tid = threadIdx.x;
  const int wave = tid >> 6, lane = tid & 63, lr = lane & 15, hg = lane >> 4;
  const int rg = wave >> 1, cg = wave & 1, fbase = cg * 12;
  const int row0 = blockIdx.x * 64;

  const f32x4 zero = {0.f, 0.f, 0.f, 0.f};
  f32x4 acc[12];
  #pragma unroll
  for (int f = 0; f < 12; ++f) acc[f] = zero;

#define QKV_STAGE(buf, k0)                                                         \
  {                                                                                \
    _Pragma("unroll")                                                              \
    for (int s = 0; s < 6; ++s){                                                   \
      int slot = s * 8 + wave;                                                     \
      int ff = slot >> 1, ks = slot & 1;                                           \
      gload16(WT + (size_t)(ff * 16 + lr) * 1024 + (k0) + ks * 32 + hg * 8,        \
              &Wl[buf][slot * 512]);                                               \
    }                                                                              \
    _Pragma("unroll")                                                              \
    for (int q = 0; q < 2; ++q){                                                   \
      int rr = (wave * 2 + q) * 4 + hg;                                            \
      int cs = lr ^ (rr & 15);                                                     \
      gload16(x + (size_t)(row0 + rr) * 1024 + (k0) + cs * 4,                      \
              &Xl[buf][(wave * 2 + q) * 256]);                                     \
    }                                                                              \
  }

  QKV_STAGE(0, 0)

  int cur = 0;
  const int xr = rg * 16 + lr;
  for (int t = 0; t < 16; ++t){
    if (t < 15){
      QKV_STAGE(cur ^ 1, (t + 1) * 64)
      asm volatile("s_waitcnt vmcnt(8)" ::: "memory");
    } else {
      asm volatile("s_waitcnt vmcnt(0)" ::: "memory");
    }
    __builtin_amdgcn_s_barrier();
    asm volatile("" ::: "memory");

    bf16x8 a[2];
    #pragma unroll
    for (int ks = 0; ks < 2; ++ks){
      int s0 = ks * 8 + hg * 2;
      f32x4 xa = *(const f32x4*)&Xl[cur][xr * 64 + ((s0 ^ lr) << 2)];
      f32x4 xb = *(const f32x4*)&Xl[cur][xr * 64 + (((s0 + 1) ^ lr) << 2)];
      a[ks][0] = f2bf(xa[0]); a[ks][1] = f2bf(xa[1]);
      a[ks][2] = f2bf(xa[2]); a[ks][3] = f2bf(xa[3]);
      a[ks][4] = f2bf(xb[0]); a[ks][5] = f2bf(xb[1]);
      a[ks][6] = f2bf(xb[2]); a[ks][7] = f2bf(xb[3]);
    }
    __builtin_amdgcn_s_setprio(1);
    #pragma unroll
    for (int fi = 0; fi < 12; ++fi){
      #pragma unroll
      for (int ks = 0; ks < 2; ++ks){
        bf16x8 bfr = *(const bf16x8*)&Wl[cur][((fbase + fi) * 2 + ks) * 512 + lane * 8];
        acc[fi] = mfma16(a[ks], bfr, acc[fi]);
      }
    }
    __builtin_amdgcn_s_setprio(0);
    asm volatile("" ::: "memory");
    __builtin_amdgcn_s_barrier();
    cur ^= 1;
  }

  #pragma unroll
  for (int fi = 0; fi < 12; ++fi){
    int f = fbase + fi;
    float bb = bias[f * 16 + lr];
    if (f < 16){
      short* dst = (f < 8) ? Qo : Ko;
      int col = (f & 7) * 16 + lr;
      #pragma unroll
      for (int r = 0; r < 4; ++r)
        dst[(size_t)(row0 + rg * 16 + hg * 4 + r) * HEAD + col] = f2bf(acc[fi][r] + bb);
    } else {
      int vcol = (f - 16) * 16 + lr;
      #pragma unroll
      for (int r = 0; r < 4; ++r)
        Vb[vcol * 72 + rg * 16 + hg * 4 + r] = f2bf(acc[fi][r] + bb);
    }
  }
  __syncthreads();
  {
    int vcol = tid >> 2, sq = tid & 3;
    bf16x8 v0 = *(const bf16x8*)&Vb[vcol * 72 + sq * 16];
    bf16x8 v1 = *(const bf16x8*)&Vb[vcol * 72 + sq * 16 + 8];
    int bb2 = row0 >> 12, ss = row0 & 4095;
    short* d = VTo + ((size_t)(bb2 * HEAD + vcol)) * S_LEN + ss + sq * 16;
    *(bf16x8*)d = v0;
    *(bf16x8*)(d + 8) = v1;
  }
}

// ---------------------------------------------------------------------------
// Kernel 2: per-wave split-KV causal flash, ZERO barriers, swapped-operand
// MFMA softmax. Each wave = 16 Q rows x one <=1024 KV chunk, step 32.
// K: double-banked register prefetch one step ahead; V: registers, issued
// early in-step. Swapped QK^T (mfma(K,Q)) puts a full q-row in each lane's
// 4-lane group: row reduce = 7 in-reg ops + 2 shuffles. Swapped PV
// (mfma(V,P)) keeps acc on q=lane&15 -> in-lane rescale. Heavy-first order.
// ---------------------------------------------------------------------------
#define PP 68

__global__ __launch_bounds__(256) void attn(const short* __restrict__ Q,
    const short* __restrict__ K, const short* __restrict__ VT,
    float* __restrict__ Opart, float* __restrict__ ML){
  __shared__ __align__(16) short Pl[4][16 * PP];

  const int wave = threadIdx.x >> 6, lane = threadIdx.x & 63;
  const int lr = lane & 15, hg = lane >> 4;
  const int wid = blockIdx.x * 4 + wave;   // 0..639, heavy (full-chunk) first
  const int b   = blockIdx.y;

  int t, c;
  if      (wid < 193) { t = 63  + wid;         c = 0; }
  else if (wid < 322) { t = 127 + (wid - 193); c = 1; }
  else if (wid < 387) { t = 191 + (wid - 322); c = 2; }
  else if (wid == 387){ t = 255;               c = 3; }
  else if (wid < 451) { t = wid - 388;         c = 0; }
  else if (wid < 514) { t = 64  + (wid - 451); c = 1; }
  else if (wid < 577) { t = 128 + (wid - 514); c = 2; }
  else                { t = 192 + (wid - 577); c = 3; }

  const int qr0  = t * 16;
  const int kvlo = c << 10;
  const int kvhi = min(kvlo + 1024, qr0 + 16);
  const int ns   = (kvhi - kvlo + 31) >> 5;   // 32-KV steps (last may be 16-padded)

  const short* Qg = Q  + ((size_t)b * S_LEN + qr0) * HEAD;
  const short* Kg = K  + (size_t)b * S_LEN * HEAD;
  const short* Vg = VT + (size_t)b * HEAD * S_LEN;

  bf16x8 qf[4];
  #pragma unroll
  for (int sl = 0; sl < 4; ++sl)
    qf[sl] = *(const bf16x8*)(Qg + (size_t)lr * HEAD + sl * 32 + hg * 8);

  const f32x4 zero = {0.f, 0.f, 0.f, 0.f};
  f32x4 acc[8];
  #pragma unroll
  for (int f = 0; f < 8; ++f) acc[f] = zero;
  float mloc = -INFINITY, den = 0.f;
  short* Pw = &Pl[wave][0];

#define LOADK(dst, j0)                                                             \
  {                                                                                \
    _Pragma("unroll")                                                              \
    for (int s = 0; s < 8; ++s)                                                    \
      dst[s] = *(const bf16x8*)(Kg + (size_t)((j0) + (s >> 2) * 16 + lr) * HEAD    \
                                + (s & 3) * 32 + hg * 8);                          \
  }

#define COMPUTE(KB, j0)                                                            \
  {                                                                                \
    /* swapped QK^T: sc[sub] lane holds S[kv = j0+sub*16+hg*4+r][q = qr0+lr] */    \
    f32x4 sc[2];                                                                   \
    _Pragma("unroll")                                                              \
    for (int sub = 0; sub < 2; ++sub){                                             \
      sc[sub] = zero;                                                              \
      _Pragma("unroll")                                                            \
      for (int sl = 0; sl < 4; ++sl)                                               \
        sc[sub] = mfma16(KB[sub * 4 + sl], qf[sl], sc[sub]);                       \
    }                                                                              \
    /* V fragments issued here: consumed ~softmax-length later */                  \
    bf16x8 vf[8];                                                                  \
    _Pragma("unroll")                                                              \
    for (int f = 0; f < 8; ++f)                                                    \
      vf[f] = *(const bf16x8*)(Vg + (size_t)(f * 16 + lr) * S_LEN + (j0) + hg * 8);\
    if ((j0) + 31 > qr0){                                                          \
      _Pragma("unroll")                                                            \
      for (int sub = 0; sub < 2; ++sub){                                           \
        int kv0 = (j0) + sub * 16 + hg * 4;                                        \
        _Pragma("unroll")                                                          \
        for (int r = 0; r < 4; ++r)                                                \
          if (kv0 + r > qr0 + lr) sc[sub][r] = -INFINITY;                          \
      }                                                                            \
    }                                                                              \
    float pm = fmaxf(fmaxf(fmaxf(sc[0][0], sc[0][1]), fmaxf(sc[0][2], sc[0][3])),  \
                     fmaxf(fmaxf(sc[1][0], sc[1][1]), fmaxf(sc[1][2], sc[1][3]))); \
    pm = fmaxf(pm, __shfl_xor(pm, 16));                                            \
    pm = fmaxf(pm, __shfl_xor(pm, 32));                                            \
    if (__any(pm > mloc + 8.0f)){                                                  \
      float mn = fmaxf(mloc, pm);                                                  \
      float al = __expf(mloc - mn);                                                \
      mloc = mn; den *= al;                                                        \
      _Pragma("unroll")                                                            \
      for (int f = 0; f < 8; ++f) acc[f] *= al;                                    \
    }                                                                              \
    float rs = 0.f;                                                                \
    s16x4 pb0, pb1;                                                                \
    _Pragma("unroll")                                                              \
    for (int r = 0; r < 4; ++r){                                                   \
      float p0 = __expf(sc[0][r] - mloc);                                          \
      float p1 = __expf(sc[1][r] - mloc);                                          \
      rs += p0 + p1;                                                               \
      pb0[r] = f2bf(p0); pb1[r] = f2bf(p1);                                        \
    }                                                                              \
    rs += __shfl_xor(rs, 16);                                                      \
    rs += __shfl_xor(rs, 32);                                                      \
    den += rs;                                                                     \
    *(s16x4*)(&Pw[lr * PP + hg * 4])      = pb0;                                   \
    *(s16x4*)(&Pw[lr * PP + 16 + hg * 4]) = pb1;                                   \
    bf16x8 pf = *(const bf16x8*)(&Pw[lr * PP + hg * 8]);                           \
    /* swapped PV: acc[f] lane holds O[q = qr0+lr][d = f*16+hg*4+r] */             \
    _Pragma("unroll")                                                              \
    for (int f = 0; f < 8; ++f) acc[f] = mfma16(vf[f], pf, acc[f]);                \
  }

  bf16x8 ka[8], kb[8];
  LOADK(ka, kvlo)
  int j = kvlo;
  for (int st = 0; st < ns; st += 2){
    if (st + 1 < ns) LOADK(kb, j + 32)
    COMPUTE(ka, j)
    if (st + 2 < ns) LOADK(ka, j + 64)
    if (st + 1 < ns) COMPUTE(kb, j + 32)
    j += 64;
  }

  // ---- write partial (unnormalized O, m, l) ----
  const int pidx = b * 640 + wid;
  float* Op = Opart + (size_t)pidx * 2048;
  #pragma unroll
  for (int f = 0; f < 8; ++f)
    *(f32x4*)(Op + lr * 128 + f * 16 + hg * 4) = acc[f];
  if (hg == 0){
    ML[pidx * 32 + lr]      = mloc;
    ML[pidx * 32 + 16 + lr] = den;
  }
}

// ---------------------------------------------------------------------------
// Kernel 3: combine partials. Block = one 16-row tile; thread = (row, 8 cols).
// ---------------------------------------------------------------------------
__global__ __launch_bounds__(256) void combine(const float* __restrict__ Opart,
    const float* __restrict__ ML, float* __restrict__ out){
  const int t = blockIdx.x, b = blockIdx.y;
  const int row = threadIdx.x >> 4, cb = threadIdx.x & 15;
  const int nc = (t >> 6) + 1;

  int iis[4];
  for (int cc = 0; cc < nc; ++cc){
    iis[cc] = (t >= 64 * cc + 63)
      ? ((cc == 0) ? t - 63 : (cc == 1) ? 193 + t - 127 : (cc == 2) ? 322 + t - 191 : 387)
      : ((cc == 0) ? 388 + t : (cc == 1) ? 451 + t - 64 : (cc == 2) ? 514 + t - 128 : 577 + t - 192);
  }

  float M = -INFINITY;
  for (int cc = 0; cc < nc; ++cc)
    M = fmaxf(M, ML[(b * 640 + iis[cc]) * 32 + row]);

  float L = 0.f;
  float o[8];
  #pragma unroll
  for (int e = 0; e < 8; ++e) o[e] = 0.f;

  for (int cc = 0; cc < nc; ++cc){
    int id = b * 640 + iis[cc];
    float mc = ML[id * 32 + row];
    float lc = ML[id * 32 + 16 + row];
    float scl = __expf(mc - M);
    L += lc * scl;
    const float* op = Opart + (size_t)id * 2048 + row * 128 + cb * 8;
    float4 v0 = *(const float4*)(op);
    float4 v1 = *(const float4*)(op + 4);
    o[0] += scl * v0.x; o[1] += scl * v0.y; o[2] += scl * v0.z; o[3] += scl * v0.w;
    o[4] += scl * v1.x; o[5] += scl * v1.y; o[6] += scl * v1.z; o[7] += scl * v1.w;
  }
  float inv = 1.f / L;
  float* dst = out + ((size_t)b * S_LEN + t * 16 + row) * HEAD + cb * 8;
  float4 w0 = { o[0] * inv, o[1] * inv, o[2] * inv, o[3] * inv };
  float4 w1 = { o[4] * inv, o[5] * inv, o[6] * inv, o[7] * inv };
  *(float4*)(dst)     = w0;
  *(float4*)(dst + 4) = w1;
}

// ---------------------------------------------------------------------------
extern "C" void kernel_launch(void* const* d_in, const int* in_sizes, int n_in,
                              void* d_out, int out_size, void* d_ws, size_t ws_size,
                              hipStream_t stream){
  const float* x  = (const float*)d_in[0];
  const float* Wq = (const float*)d_in[1];
  const float* bq = (const float*)d_in[2];
  const float* Wk = (const float*)d_in[3];
  const float* bk = (const float*)d_in[4];
  const float* Wv = (const float*)d_in[5];
  const float* bv = (const float*)d_in[6];
  float* out = (float*)d_out;

  char* ws = (char*)d_ws;
  short* WT    = (short*)(ws);                         // 768 KB
  float* bias  = (float*)(ws + 786432);                // 1.5 KB
  short* Qb    = (short*)(ws + (1u << 20));            // 4 MB
  short* Kb    = (short*)(ws + (1u << 20) + 4194304u); // 4 MB
  short* VTb   = (short*)(ws + (1u << 20) + 8388608u); // 4 MB
  float* Opart = (float*)(ws + 13631488u);             // 2560*8KB = 20 MB
  float* ML    = (float*)(ws + 13631488u + 20971520u); // 320 KB

  prep_w<<<1536, 256, 0, stream>>>(Wq, bq, Wk, bk, Wv, bv, WT, bias);
  qkv_proj<<<256, 512, 0, stream>>>(x, WT, bias, Qb, Kb, VTb);
  attn<<<dim3(160, 4), 256, 0, stream>>>(Qb, Kb, VTb, Opart, ML);
  combine<<<dim3(256, 4), 256, 0, stream>>>(Opart, ML, out);
}

// Round 7
// 112.990 us; speedup vs baseline: 2.0337x; 2.0337x over previous
//
#include <hip/hip_runtime.h>
#include <hip/hip_bf16.h>
#include <math.h>

#define S_LEN 4096
#define EMB   1024
#define HEAD  128

typedef short bf16x8 __attribute__((ext_vector_type(8)));
typedef short s16x4  __attribute__((ext_vector_type(4)));
typedef float f32x4  __attribute__((ext_vector_type(4)));

static __device__ __forceinline__ short f2bf(float x){
  unsigned u = __builtin_bit_cast(unsigned, x);
  u += 0x7fffu + ((u >> 16) & 1u);
  return (short)(u >> 16);
}
static __device__ __forceinline__ f32x4 mfma16(bf16x8 a, bf16x8 b, f32x4 c){
  return __builtin_amdgcn_mfma_f32_16x16x32_bf16(a, b, c, 0, 0, 0);
}
static __device__ __forceinline__ void gload16(const void* g, void* l){
  __builtin_amdgcn_global_load_lds((const __attribute__((address_space(1))) unsigned*)g,
                                   (__attribute__((address_space(3))) unsigned*)l, 16, 0, 0);
}

// ---------------------------------------------------------------------------
// Kernel 0: WT_cat[384][1024] bf16 (transposed, Q pre-scaled by 1/sqrt(128)),
// bias_cat[384] f32.
// ---------------------------------------------------------------------------
__global__ void prep_w(const float* __restrict__ Wq, const float* __restrict__ bq,
                       const float* __restrict__ Wk, const float* __restrict__ bk,
                       const float* __restrict__ Wv, const float* __restrict__ bv,
                       short* __restrict__ WT, float* __restrict__ bias){
  int idx = blockIdx.x * 256 + threadIdx.x;
  int nc  = idx >> 10;
  int k   = idx & 1023;
  int mat = nc >> 7;
  int n   = nc & 127;
  const float* W = (mat == 0) ? Wq : (mat == 1) ? Wk : Wv;
  float s = (mat == 0) ? 0.08838834764831845f : 1.0f;
  WT[idx] = f2bf(W[k * HEAD + n] * s);
  if (idx < 384){
    int m2 = idx >> 7, n2 = idx & 127;
    const float* bsrc = (m2 == 0) ? bq : (m2 == 1) ? bk : bv;
    float s2 = (m2 == 0) ? 0.08838834764831845f : 1.0f;
    bias[idx] = bsrc[n2] * s2;
  }
}

// ---------------------------------------------------------------------------
// Kernel 1: fused QKV projection (verified round-4/5 structure, unchanged).
// ---------------------------------------------------------------------------
__global__ __launch_bounds__(512) void qkv_proj(const float* __restrict__ x,
    const short* __restrict__ WT, const float* __restrict__ bias,
    short* __restrict__ Qo, short* __restrict__ Ko, short* __restrict__ VTo){
  __shared__ __align__(16) short Wl[2][24576];   // 48KB each
  __shared__ __align__(16) float Xl[2][4096];    // 16KB each
  __shared__ __align__(16) short Vb[128 * 72];   // 18KB bounce

  const int tid = threadIdx.x;
  const int wave = tid >> 6, lane = tid & 63, lr = lane & 15, hg = lane >> 4;
  const int rg = wave >> 1, cg = wave & 1, fbase = cg * 12;
  const int row0 = blockIdx.x * 64;

  const f32x4 zero = {0.f, 0.f, 0.f, 0.f};
  f32x4 acc[12];
  #pragma unroll
  for (int f = 0; f < 12; ++f) acc[f] = zero;

#define QKV_STAGE(buf, k0)                                                         \
  {                                                                                \
    _Pragma("unroll")                                                              \
    for (int s = 0; s < 6; ++s){                                                   \
      int slot = s * 8 + wave;                                                     \
      int ff = slot >> 1, ks = slot & 1;                                           \
      gload16(WT + (size_t)(ff * 16 + lr) * 1024 + (k0) + ks * 32 + hg * 8,        \
              &Wl[buf][slot * 512]);                                               \
    }                                                                              \
    _Pragma("unroll")                                                              \
    for (int q = 0; q < 2; ++q){                                                   \
      int rr = (wave * 2 + q) * 4 + hg;                                            \
      int cs = lr ^ (rr & 15);                                                     \
      gload16(x + (size_t)(row0 + rr) * 1024 + (k0) + cs * 4,                      \
              &Xl[buf][(wave * 2 + q) * 256]);                                     \
    }                                                                              \
  }

  QKV_STAGE(0, 0)

  int cur = 0;
  const int xr = rg * 16 + lr;
  for (int t = 0; t < 16; ++t){
    if (t < 15){
      QKV_STAGE(cur ^ 1, (t + 1) * 64)
      asm volatile("s_waitcnt vmcnt(8)" ::: "memory");
    } else {
      asm volatile("s_waitcnt vmcnt(0)" ::: "memory");
    }
    __builtin_amdgcn_s_barrier();
    asm volatile("" ::: "memory");

    bf16x8 a[2];
    #pragma unroll
    for (int ks = 0; ks < 2; ++ks){
      int s0 = ks * 8 + hg * 2;
      f32x4 xa = *(const f32x4*)&Xl[cur][xr * 64 + ((s0 ^ lr) << 2)];
      f32x4 xb = *(const f32x4*)&Xl[cur][xr * 64 + (((s0 + 1) ^ lr) << 2)];
      a[ks][0] = f2bf(xa[0]); a[ks][1] = f2bf(xa[1]);
      a[ks][2] = f2bf(xa[2]); a[ks][3] = f2bf(xa[3]);
      a[ks][4] = f2bf(xb[0]); a[ks][5] = f2bf(xb[1]);
      a[ks][6] = f2bf(xb[2]); a[ks][7] = f2bf(xb[3]);
    }
    __builtin_amdgcn_s_setprio(1);
    #pragma unroll
    for (int fi = 0; fi < 12; ++fi){
      #pragma unroll
      for (int ks = 0; ks < 2; ++ks){
        bf16x8 bfr = *(const bf16x8*)&Wl[cur][((fbase + fi) * 2 + ks) * 512 + lane * 8];
        acc[fi] = mfma16(a[ks], bfr, acc[fi]);
      }
    }
    __builtin_amdgcn_s_setprio(0);
    asm volatile("" ::: "memory");
    __builtin_amdgcn_s_barrier();
    cur ^= 1;
  }

  #pragma unroll
  for (int fi = 0; fi < 12; ++fi){
    int f = fbase + fi;
    float bb = bias[f * 16 + lr];
    if (f < 16){
      short* dst = (f < 8) ? Qo : Ko;
      int col = (f & 7) * 16 + lr;
      #pragma unroll
      for (int r = 0; r < 4; ++r)
        dst[(size_t)(row0 + rg * 16 + hg * 4 + r) * HEAD + col] = f2bf(acc[fi][r] + bb);
    } else {
      int vcol = (f - 16) * 16 + lr;
      #pragma unroll
      for (int r = 0; r < 4; ++r)
        Vb[vcol * 72 + rg * 16 + hg * 4 + r] = f2bf(acc[fi][r] + bb);
    }
  }
  __syncthreads();
  {
    int vcol = tid >> 2, sq = tid & 3;
    bf16x8 v0 = *(const bf16x8*)&Vb[vcol * 72 + sq * 16];
    bf16x8 v1 = *(const bf16x8*)&Vb[vcol * 72 + sq * 16 + 8];
    int bb2 = row0 >> 12, ss = row0 & 4095;
    short* d = VTo + ((size_t)(bb2 * HEAD + vcol)) * S_LEN + ss + sq * 16;
    *(bf16x8*)d = v0;
    *(bf16x8*)(d + 8) = v1;
  }
}

// ---------------------------------------------------------------------------
// Kernel 2: split-KV causal flash. Round-4 skeleton (LDS staging via
// global_load_lds, fragment-ordered slots, heavy-first map) + swapped-operand
// core (round-6 validated) + KV step 32 so LDS = 37KB -> 4 blocks/CU at
// VGPR<=128 (launch_bounds(256,4)). Counted vmcnt, 2 barriers/step.
// ---------------------------------------------------------------------------
#define PPS 36   // P row pitch (shorts): [16 q][32 kv + 4 pad]

__global__ __launch_bounds__(256, 4) void attn(const short* __restrict__ Q,
    const short* __restrict__ K, const short* __restrict__ VT,
    float* __restrict__ Opart, float* __restrict__ ML){
  __shared__ __align__(16) short Kl[2][4096];       // 8 slots x 512 shorts
  __shared__ __align__(16) short Vl[2][4096];       // 8 slots x 512 shorts
  __shared__ __align__(16) short Pl[4][16 * PPS];   // per-wave P^T buffer

  const int tid = threadIdx.x;
  const int wave = tid >> 6, lane = tid & 63, lr = lane & 15, hg = lane >> 4;
  const int b = blockIdx.y;
  const int i = blockIdx.x;

  // heavy-first map i -> (t, c): full-16-step (1024-KV) items first
  int t, c;
  if      (i < 49)  { t = 15 + i;       c = 0; }
  else if (i < 82)  { t = 31 + (i - 49); c = 1; }
  else if (i < 99)  { t = 47 + (i - 82); c = 2; }
  else if (i < 100) { t = 63;            c = 3; }
  else if (i < 115) { t = i - 100;       c = 0; }
  else if (i < 130) { t = 16 + (i - 115); c = 1; }
  else if (i < 145) { t = 32 + (i - 130); c = 2; }
  else              { t = 48 + (i - 145); c = 3; }

  const int qt0  = t * 64;
  const int kvlo = c * 1024;
  const int kvhi = min(kvlo + 1024, qt0 + 64);
  const int ns   = (kvhi - kvlo) >> 5;          // 32-KV steps, always even

  const int qr0w = qt0 + wave * 16;             // this wave's 16 q rows
  const short* Qg = Q  + ((size_t)b * S_LEN + qr0w) * HEAD;
  const short* Kg = K  + (size_t)b * S_LEN * HEAD;
  const short* Vg = VT + (size_t)b * HEAD * S_LEN;

  // Q as B-operand: col=q=lr, k = d = sl*32 + hg*8 + e
  bf16x8 qf[4];
  #pragma unroll
  for (int sl = 0; sl < 4; ++sl)
    qf[sl] = *(const bf16x8*)(Qg + (size_t)lr * HEAD + sl * 32 + hg * 8);

  // wave stages K slots {2w,2w+1} and V slots {2w,2w+1}: 4 gloads/step
#define ATTN_STAGE(buf, j0)                                                        \
  {                                                                                \
    _Pragma("unroll")                                                              \
    for (int q = 0; q < 2; ++q){                                                   \
      int s = wave * 2 + q;                                                        \
      int kvs = s >> 2, sl = s & 3;                                                \
      gload16(Kg + (size_t)((j0) + kvs * 16 + lr) * HEAD + sl * 32 + hg * 8,       \
              &Kl[buf][s * 512]);                                                  \
    }                                                                              \
    _Pragma("unroll")                                                              \
    for (int q = 0; q < 2; ++q){                                                   \
      int s = wave * 2 + q;                                                        \
      gload16(Vg + (size_t)(s * 16 + lr) * S_LEN + (j0) + hg * 8,                  \
              &Vl[buf][s * 512]);                                                  \
    }                                                                              \
  }

  ATTN_STAGE(0, kvlo)

  const f32x4 zero = {0.f, 0.f, 0.f, 0.f};
  f32x4 acc[8];
  #pragma unroll
  for (int f = 0; f < 8; ++f) acc[f] = zero;
  float mloc = -INFINITY, den = 0.f;
  short* Pw = &Pl[wave][0];

  int cur = 0;
  for (int st = 0; st < ns; ++st){
    const int j0 = kvlo + st * 32;
    if (st + 1 < ns){
      ATTN_STAGE(cur ^ 1, j0 + 32)
      asm volatile("s_waitcnt vmcnt(4)" ::: "memory");
    } else {
      asm volatile("s_waitcnt vmcnt(0)" ::: "memory");
    }
    __builtin_amdgcn_s_barrier();
    asm volatile("" ::: "memory");

    // ---- swapped QK^T: lane holds S[kv = kvs*16+hg*4+r][q = qr0w+lr] ----
    f32x4 sc[2];
    __builtin_amdgcn_s_setprio(1);
    #pragma unroll
    for (int kvs = 0; kvs < 2; ++kvs){
      sc[kvs] = zero;
      #pragma unroll
      for (int sl = 0; sl < 4; ++sl){
        bf16x8 kf = *(const bf16x8*)&Kl[cur][(kvs * 4 + sl) * 512 + lane * 8];
        sc[kvs] = mfma16(kf, qf[sl], sc[kvs]);
      }
    }
    __builtin_amdgcn_s_setprio(0);

    // ---- causal mask ----
    if (j0 + 31 > qr0w){
      #pragma unroll
      for (int kvs = 0; kvs < 2; ++kvs){
        int kv0 = j0 + kvs * 16 + hg * 4;
        #pragma unroll
        for (int r = 0; r < 4; ++r)
          if (kv0 + r > qr0w + lr) sc[kvs][r] = -INFINITY;
      }
    }

    // ---- row max: 7 in-reg + 2 shuffle rounds ----
    float pm = fmaxf(fmaxf(fmaxf(sc[0][0], sc[0][1]), fmaxf(sc[0][2], sc[0][3])),
                     fmaxf(fmaxf(sc[1][0], sc[1][1]), fmaxf(sc[1][2], sc[1][3])));
    pm = fmaxf(pm, __shfl_xor(pm, 16));
    pm = fmaxf(pm, __shfl_xor(pm, 32));

    // ---- defer-max rescale (THR=8) ----
    if (__any(pm > mloc + 8.0f)){
      float mn = fmaxf(mloc, pm);
      float al = __expf(mloc - mn);
      mloc = mn; den *= al;
      #pragma unroll
      for (int f = 0; f < 8; ++f) acc[f] *= al;
    }

    // ---- exp + row sum ----
    float rs = 0.f;
    s16x4 pb0, pb1;
    #pragma unroll
    for (int r = 0; r < 4; ++r){
      float p0 = __expf(sc[0][r] - mloc);
      float p1 = __expf(sc[1][r] - mloc);
      rs += p0 + p1;
      pb0[r] = f2bf(p0); pb1[r] = f2bf(p1);
    }
    rs += __shfl_xor(rs, 16);
    rs += __shfl_xor(rs, 32);
    den += rs;

    // ---- P^T bounce (per-wave, in-order LDS, no barrier) ----
    *(s16x4*)(&Pw[lr * PPS + hg * 4])      = pb0;
    *(s16x4*)(&Pw[lr * PPS + 16 + hg * 4]) = pb1;
    bf16x8 pf = *(const bf16x8*)(&Pw[lr * PPS + hg * 8]);

    // ---- swapped PV: acc[f] lane holds O[d = f*16+hg*4+r][q = qr0w+lr] ----
    __builtin_amdgcn_s_setprio(1);
    #pragma unroll
    for (int f = 0; f < 8; ++f){
      bf16x8 vf = *(const bf16x8*)&Vl[cur][f * 512 + lane * 8];
      acc[f] = mfma16(vf, pf, acc[f]);
    }
    __builtin_amdgcn_s_setprio(0);

    asm volatile("" ::: "memory");
    __builtin_amdgcn_s_barrier();
    cur ^= 1;
  }

  // ---- write partial (unnormalized O, m, l) — same layout as round 4 ----
  const int pidx = b * 160 + i;
  float* Op = Opart + (size_t)pidx * 8192;
  #pragma unroll
  for (int f = 0; f < 8; ++f)
    *(f32x4*)(Op + (wave * 16 + lr) * 128 + f * 16 + hg * 4) = acc[f];
  if (hg == 0){
    ML[pidx * 128 + wave * 16 + lr]      = mloc;
    ML[pidx * 128 + 64 + wave * 16 + lr] = den;
  }
}

// ---------------------------------------------------------------------------
// Kernel 3: combine partials (round-4 verbatim). Block = one 64-row tile.
// ---------------------------------------------------------------------------
__global__ __launch_bounds__(512) void combine(const float* __restrict__ Opart,
    const float* __restrict__ ML, float* __restrict__ out){
  const int t = blockIdx.x, b = blockIdx.y;
  const int row = threadIdx.x >> 3;
  const int cgp = threadIdx.x & 7;
  const int nc = (t >> 4) + 1;
  const int fb0 = 0, fb1 = 49, fb2 = 82, fb3 = 99;

  float M = -INFINITY;
  for (int cc = 0; cc < nc; ++cc){
    int fbv = (cc == 0) ? fb0 : (cc == 1) ? fb1 : (cc == 2) ? fb2 : fb3;
    int ii = (t >= 16 * cc + 15) ? (fbv + t - (16 * cc + 15)) : (100 + t - cc);
    M = fmaxf(M, ML[(b * 160 + ii) * 128 + row]);
  }
  float L = 0.f;
  float o[16];
  #pragma unroll
  for (int e = 0; e < 16; ++e) o[e] = 0.f;
  for (int cc = 0; cc < nc; ++cc){
    int fbv = (cc == 0) ? fb0 : (cc == 1) ? fb1 : (cc == 2) ? fb2 : fb3;
    int ii = (t >= 16 * cc + 15) ? (fbv + t - (16 * cc + 15)) : (100 + t - cc);
    int id = b * 160 + ii;
    float mc = ML[id * 128 + row];
    float lc = ML[id * 128 + 64 + row];
    float s = __expf(mc - M);
    L += lc * s;
    const float* op = Opart + (size_t)id * 8192 + row * 128 + cgp * 16;
    #pragma unroll
    for (int e4 = 0; e4 < 4; ++e4){
      float4 v = *(const float4*)(op + e4 * 4);
      o[e4*4+0] += s * v.x; o[e4*4+1] += s * v.y;
      o[e4*4+2] += s * v.z; o[e4*4+3] += s * v.w;
    }
  }
  float inv = 1.f / L;
  float* dst = out + ((size_t)b * S_LEN + t * 64 + row) * HEAD + cgp * 16;
  #pragma unroll
  for (int e4 = 0; e4 < 4; ++e4){
    float4 w = { o[e4*4]*inv, o[e4*4+1]*inv, o[e4*4+2]*inv, o[e4*4+3]*inv };
    *(float4*)(dst + e4 * 4) = w;
  }
}

// ---------------------------------------------------------------------------
extern "C" void kernel_launch(void* const* d_in, const int* in_sizes, int n_in,
                              void* d_out, int out_size, void* d_ws, size_t ws_size,
                              hipStream_t stream){
  const float* x  = (const float*)d_in[0];
  const float* Wq = (const float*)d_in[1];
  const float* bq = (const float*)d_in[2];
  const float* Wk = (const float*)d_in[3];
  const float* bk = (const float*)d_in[4];
  const float* Wv = (const float*)d_in[5];
  const float* bv = (const float*)d_in[6];
  float* out = (float*)d_out;

  char* ws = (char*)d_ws;
  short* WT    = (short*)(ws);                         // 768 KB
  float* bias  = (float*)(ws + 786432);                // 1.5 KB
  short* Qb    = (short*)(ws + (1u << 20));            // 4 MB
  short* Kb    = (short*)(ws + (1u << 20) + 4194304u); // 4 MB
  short* VTb   = (short*)(ws + (1u << 20) + 8388608u); // 4 MB
  float* Opart = (float*)(ws + 13631488u);             // 640*32KB = 20 MB
  float* ML    = (float*)(ws + 13631488u + 20971520u); // 320 KB

  prep_w<<<1536, 256, 0, stream>>>(Wq, bq, Wk, bk, Wv, bv, WT, bias);
  qkv_proj<<<256, 512, 0, stream>>>(x, WT, bias, Qb, Kb, VTb);
  attn<<<dim3(160, 4), 256, 0, stream>>>(Qb, Kb, VTb, Opart, ML);
  combine<<<dim3(64, 4), 512, 0, stream>>>(Opart, ML, out);
}

// Round 8
// 112.581 us; speedup vs baseline: 2.0411x; 1.0036x over previous
//
#include <hip/hip_runtime.h>
#include <hip/hip_bf16.h>
#include <math.h>

#define S_LEN 4096
#define EMB   1024
#define HEAD  128

typedef short bf16x8 __attribute__((ext_vector_type(8)));
typedef short s16x4  __attribute__((ext_vector_type(4)));
typedef float f32x4  __attribute__((ext_vector_type(4)));

static __device__ __forceinline__ short f2bf(float x){
  unsigned u = __builtin_bit_cast(unsigned, x);
  u += 0x7fffu + ((u >> 16) & 1u);
  return (short)(u >> 16);
}
static __device__ __forceinline__ float bf2f(short s){
  unsigned u = ((unsigned)(unsigned short)s) << 16;
  return __builtin_bit_cast(float, u);
}
static __device__ __forceinline__ f32x4 mfma16(bf16x8 a, bf16x8 b, f32x4 c){
  return __builtin_amdgcn_mfma_f32_16x16x32_bf16(a, b, c, 0, 0, 0);
}
static __device__ __forceinline__ void gload16(const void* g, void* l){
  __builtin_amdgcn_global_load_lds((const __attribute__((address_space(1))) unsigned*)g,
                                   (__attribute__((address_space(3))) unsigned*)l, 16, 0, 0);
}

// ---------------------------------------------------------------------------
// Kernel 0: WT_cat[384][1024] bf16 (transposed, Q pre-scaled by 1/sqrt(128)),
// bias_cat[384] f32.
// ---------------------------------------------------------------------------
__global__ void prep_w(const float* __restrict__ Wq, const float* __restrict__ bq,
                       const float* __restrict__ Wk, const float* __restrict__ bk,
                       const float* __restrict__ Wv, const float* __restrict__ bv,
                       short* __restrict__ WT, float* __restrict__ bias){
  int idx = blockIdx.x * 256 + threadIdx.x;
  int nc  = idx >> 10;
  int k   = idx & 1023;
  int mat = nc >> 7;
  int n   = nc & 127;
  const float* W = (mat == 0) ? Wq : (mat == 1) ? Wk : Wv;
  float s = (mat == 0) ? 0.08838834764831845f : 1.0f;
  WT[idx] = f2bf(W[k * HEAD + n] * s);
  if (idx < 384){
    int m2 = idx >> 7, n2 = idx & 127;
    const float* bsrc = (m2 == 0) ? bq : (m2 == 1) ? bk : bv;
    float s2 = (m2 == 0) ? 0.08838834764831845f : 1.0f;
    bias[idx] = bsrc[n2] * s2;
  }
}

// ---------------------------------------------------------------------------
// Kernel 1: fused QKV projection. Staging identical to round 4/5/7 (verified).
// Wave remap 4x2 -> 2 rowgroups x 4 colgroups: each wave 32 rows x 6 frags,
// W fragment read once, used by 2 row-frags -> LDS read traffic 224->160KB/step.
// ---------------------------------------------------------------------------
__global__ __launch_bounds__(512) void qkv_proj(const float* __restrict__ x,
    const short* __restrict__ WT, const float* __restrict__ bias,
    short* __restrict__ Qo, short* __restrict__ Ko, short* __restrict__ VTo){
  __shared__ __align__(16) short Wl[2][24576];   // 48KB each
  __shared__ __align__(16) float Xl[2][4096];    // 16KB each
  __shared__ __align__(16) short Vb[128 * 72];   // 18KB bounce

  const int tid = threadIdx.x;
  const int wave = tid >> 6, lane = tid & 63, lr = lane & 15, hg = lane >> 4;
  const int wrg = wave >> 2, cg = wave & 3, fbase = cg * 6;
  const int row0 = blockIdx.x * 64;

  const f32x4 zero = {0.f, 0.f, 0.f, 0.f};
  f32x4 acc[2][6];
  #pragma unroll
  for (int rf = 0; rf < 2; ++rf)
    #pragma unroll
    for (int f = 0; f < 6; ++f) acc[rf][f] = zero;

#define QKV_STAGE(buf, k0)                                                         \
  {                                                                                \
    _Pragma("unroll")                                                              \
    for (int s = 0; s < 6; ++s){                                                   \
      int slot = s * 8 + wave;                                                     \
      int ff = slot >> 1, ks = slot & 1;                                           \
      gload16(WT + (size_t)(ff * 16 + lr) * 1024 + (k0) + ks * 32 + hg * 8,        \
              &Wl[buf][slot * 512]);                                               \
    }                                                                              \
    _Pragma("unroll")                                                              \
    for (int q = 0; q < 2; ++q){                                                   \
      int rr = (wave * 2 + q) * 4 + hg;                                            \
      int cs = lr ^ (rr & 15);                                                     \
      gload16(x + (size_t)(row0 + rr) * 1024 + (k0) + cs * 4,                      \
              &Xl[buf][(wave * 2 + q) * 256]);                                     \
    }                                                                              \
  }

  QKV_STAGE(0, 0)

  int cur = 0;
  for (int t = 0; t < 16; ++t){
    if (t < 15){
      QKV_STAGE(cur ^ 1, (t + 1) * 64)
      asm volatile("s_waitcnt vmcnt(8)" ::: "memory");
    } else {
      asm volatile("s_waitcnt vmcnt(0)" ::: "memory");
    }
    __builtin_amdgcn_s_barrier();
    asm volatile("" ::: "memory");

    bf16x8 a[2][2];
    #pragma unroll
    for (int rf = 0; rf < 2; ++rf){
      const int xr = wrg * 32 + rf * 16 + lr;
      #pragma unroll
      for (int ks = 0; ks < 2; ++ks){
        int s0 = ks * 8 + hg * 2;
        f32x4 xa = *(const f32x4*)&Xl[cur][xr * 64 + ((s0 ^ lr) << 2)];
        f32x4 xb = *(const f32x4*)&Xl[cur][xr * 64 + (((s0 + 1) ^ lr) << 2)];
        a[rf][ks][0] = f2bf(xa[0]); a[rf][ks][1] = f2bf(xa[1]);
        a[rf][ks][2] = f2bf(xa[2]); a[rf][ks][3] = f2bf(xa[3]);
        a[rf][ks][4] = f2bf(xb[0]); a[rf][ks][5] = f2bf(xb[1]);
        a[rf][ks][6] = f2bf(xb[2]); a[rf][ks][7] = f2bf(xb[3]);
      }
    }
    __builtin_amdgcn_s_setprio(1);
    #pragma unroll
    for (int fi = 0; fi < 6; ++fi){
      #pragma unroll
      for (int ks = 0; ks < 2; ++ks){
        bf16x8 bfr = *(const bf16x8*)&Wl[cur][((fbase + fi) * 2 + ks) * 512 + lane * 8];
        acc[0][fi] = mfma16(a[0][ks], bfr, acc[0][fi]);
        acc[1][fi] = mfma16(a[1][ks], bfr, acc[1][fi]);
      }
    }
    __builtin_amdgcn_s_setprio(0);
    asm volatile("" ::: "memory");
    __builtin_amdgcn_s_barrier();
    cur ^= 1;
  }

  #pragma unroll
  for (int rf = 0; rf < 2; ++rf){
    #pragma unroll
    for (int fi = 0; fi < 6; ++fi){
      int f = fbase + fi;
      float bb = bias[f * 16 + lr];
      int rbase = row0 + wrg * 32 + rf * 16 + hg * 4;
      if (f < 16){
        short* dst = (f < 8) ? Qo : Ko;
        int col = (f & 7) * 16 + lr;
        #pragma unroll
        for (int r = 0; r < 4; ++r)
          dst[(size_t)(rbase + r) * HEAD + col] = f2bf(acc[rf][fi][r] + bb);
      } else {
        int vcol = (f - 16) * 16 + lr;
        #pragma unroll
        for (int r = 0; r < 4; ++r)
          Vb[vcol * 72 + wrg * 32 + rf * 16 + hg * 4 + r] = f2bf(acc[rf][fi][r] + bb);
      }
    }
  }
  __syncthreads();
  {
    int vcol = tid >> 2, sq = tid & 3;
    bf16x8 v0 = *(const bf16x8*)&Vb[vcol * 72 + sq * 16];
    bf16x8 v1 = *(const bf16x8*)&Vb[vcol * 72 + sq * 16 + 8];
    int bb2 = row0 >> 12, ss = row0 & 4095;
    short* d = VTo + ((size_t)(bb2 * HEAD + vcol)) * S_LEN + ss + sq * 16;
    *(bf16x8*)d = v0;
    *(bf16x8*)(d + 8) = v1;
  }
}

// ---------------------------------------------------------------------------
// Kernel 2: split-KV causal flash, chunk 512 (288 items/batch, 1152 blocks).
// Round-7 verified core (swapped operands, LDS staging, counted vmcnt,
// defer-max). Partials stored NORMALIZED in bf16 (O/den) to fit ws.
// Heavy-first map: off[c] = c*(61-4c), 232 heavy + 56 partial items.
// ---------------------------------------------------------------------------
#define PPS 36

__global__ __launch_bounds__(256, 4) void attn(const short* __restrict__ Q,
    const short* __restrict__ K, const short* __restrict__ VT,
    short* __restrict__ Opart, float* __restrict__ ML){
  __shared__ __align__(16) short Kl[2][4096];
  __shared__ __align__(16) short Vl[2][4096];
  __shared__ __align__(16) short Pl[4][16 * PPS];

  const int tid = threadIdx.x;
  const int wave = tid >> 6, lane = tid & 63, lr = lane & 15, hg = lane >> 4;
  const int b = blockIdx.x;     // batch fast -> heavy items of all batches first
  const int i = blockIdx.y;     // 0..287 heavy-first

  int t, c;
  if (i < 232){
    c = 0;
    #pragma unroll
    for (int j = 1; j < 8; ++j) if (i >= j * (61 - 4 * j)) c = j;
    t = 8 * c + 7 + (i - c * (61 - 4 * c));
  } else {
    int p = i - 232;
    t = p + p / 7;
    c = t >> 3;
  }

  const int qt0  = t * 64;
  const int kvlo = c << 9;
  const int kvhi = min(kvlo + 512, qt0 + 64);
  const int ns   = (kvhi - kvlo) >> 5;          // 32-KV steps, always even

  const int qr0w = qt0 + wave * 16;
  const short* Qg = Q  + ((size_t)b * S_LEN + qr0w) * HEAD;
  const short* Kg = K  + (size_t)b * S_LEN * HEAD;
  const short* Vg = VT + (size_t)b * HEAD * S_LEN;

  bf16x8 qf[4];
  #pragma unroll
  for (int sl = 0; sl < 4; ++sl)
    qf[sl] = *(const bf16x8*)(Qg + (size_t)lr * HEAD + sl * 32 + hg * 8);

#define ATTN_STAGE(buf, j0)                                                        \
  {                                                                                \
    _Pragma("unroll")                                                              \
    for (int q = 0; q < 2; ++q){                                                   \
      int s = wave * 2 + q;                                                        \
      int kvs = s >> 2, sl = s & 3;                                                \
      gload16(Kg + (size_t)((j0) + kvs * 16 + lr) * HEAD + sl * 32 + hg * 8,       \
              &Kl[buf][s * 512]);                                                  \
    }                                                                              \
    _Pragma("unroll")                                                              \
    for (int q = 0; q < 2; ++q){                                                   \
      int s = wave * 2 + q;                                                        \
      gload16(Vg + (size_t)(s * 16 + lr) * S_LEN + (j0) + hg * 8,                  \
              &Vl[buf][s * 512]);                                                  \
    }                                                                              \
  }

  ATTN_STAGE(0, kvlo)

  const f32x4 zero = {0.f, 0.f, 0.f, 0.f};
  f32x4 acc[8];
  #pragma unroll
  for (int f = 0; f < 8; ++f) acc[f] = zero;
  float mloc = -INFINITY, den = 0.f;
  short* Pw = &Pl[wave][0];

  int cur = 0;
  for (int st = 0; st < ns; ++st){
    const int j0 = kvlo + st * 32;
    if (st + 1 < ns){
      ATTN_STAGE(cur ^ 1, j0 + 32)
      asm volatile("s_waitcnt vmcnt(4)" ::: "memory");
    } else {
      asm volatile("s_waitcnt vmcnt(0)" ::: "memory");
    }
    __builtin_amdgcn_s_barrier();
    asm volatile("" ::: "memory");

    f32x4 sc[2];
    __builtin_amdgcn_s_setprio(1);
    #pragma unroll
    for (int kvs = 0; kvs < 2; ++kvs){
      sc[kvs] = zero;
      #pragma unroll
      for (int sl = 0; sl < 4; ++sl){
        bf16x8 kf = *(const bf16x8*)&Kl[cur][(kvs * 4 + sl) * 512 + lane * 8];
        sc[kvs] = mfma16(kf, qf[sl], sc[kvs]);
      }
    }
    __builtin_amdgcn_s_setprio(0);

    if (j0 + 31 > qr0w){
      #pragma unroll
      for (int kvs = 0; kvs < 2; ++kvs){
        int kv0 = j0 + kvs * 16 + hg * 4;
        #pragma unroll
        for (int r = 0; r < 4; ++r)
          if (kv0 + r > qr0w + lr) sc[kvs][r] = -INFINITY;
      }
    }

    float pm = fmaxf(fmaxf(fmaxf(sc[0][0], sc[0][1]), fmaxf(sc[0][2], sc[0][3])),
                     fmaxf(fmaxf(sc[1][0], sc[1][1]), fmaxf(sc[1][2], sc[1][3])));
    pm = fmaxf(pm, __shfl_xor(pm, 16));
    pm = fmaxf(pm, __shfl_xor(pm, 32));

    if (__any(pm > mloc + 8.0f)){
      float mn = fmaxf(mloc, pm);
      float al = __expf(mloc - mn);
      mloc = mn; den *= al;
      #pragma unroll
      for (int f = 0; f < 8; ++f) acc[f] *= al;
    }

    float rs = 0.f;
    s16x4 pb0, pb1;
    #pragma unroll
    for (int r = 0; r < 4; ++r){
      float p0 = __expf(sc[0][r] - mloc);
      float p1 = __expf(sc[1][r] - mloc);
      rs += p0 + p1;
      pb0[r] = f2bf(p0); pb1[r] = f2bf(p1);
    }
    rs += __shfl_xor(rs, 16);
    rs += __shfl_xor(rs, 32);
    den += rs;

    *(s16x4*)(&Pw[lr * PPS + hg * 4])      = pb0;
    *(s16x4*)(&Pw[lr * PPS + 16 + hg * 4]) = pb1;
    bf16x8 pf = *(const bf16x8*)(&Pw[lr * PPS + hg * 8]);

    __builtin_amdgcn_s_setprio(1);
    #pragma unroll
    for (int f = 0; f < 8; ++f){
      bf16x8 vf = *(const bf16x8*)&Vl[cur][f * 512 + lane * 8];
      acc[f] = mfma16(vf, pf, acc[f]);
    }
    __builtin_amdgcn_s_setprio(0);

    asm volatile("" ::: "memory");
    __builtin_amdgcn_s_barrier();
    cur ^= 1;
  }

  // ---- write NORMALIZED partial (bf16 O/den) + (m, den) ----
  const int pidx = b * 288 + i;
  const float inv = 1.0f / den;
  short* Op = Opart + (size_t)pidx * 8192;
  #pragma unroll
  for (int f = 0; f < 8; ++f){
    s16x4 ov;
    #pragma unroll
    for (int r = 0; r < 4; ++r) ov[r] = f2bf(acc[f][r] * inv);
    *(s16x4*)(Op + (wave * 16 + lr) * 128 + f * 16 + hg * 4) = ov;
  }
  if (hg == 0){
    ML[pidx * 128 + wave * 16 + lr]      = mloc;
    ML[pidx * 128 + 64 + wave * 16 + lr] = den;
  }
}

// ---------------------------------------------------------------------------
// Kernel 3: combine normalized bf16 partials. Block = one 64-row tile.
// weight_i = exp(m_i - M) * l_i ; out = sum(w_i * Ohat_i) / sum(w_i).
// ---------------------------------------------------------------------------
__global__ __launch_bounds__(512) void combine(const short* __restrict__ Opart,
    const float* __restrict__ ML, float* __restrict__ out){
  const int t = blockIdx.x, b = blockIdx.y;
  const int row = threadIdx.x >> 3;
  const int cgp = threadIdx.x & 7;
  const int nc = (t >> 3) + 1;
  const int nheavy = (t + 1) >> 3;

  float M = -INFINITY;
  for (int cc = 0; cc < nc; ++cc){
    int ii = (cc < nheavy) ? cc * (61 - 4 * cc) + t - (8 * cc + 7)
                           : 232 + t - (t >> 3);
    M = fmaxf(M, ML[(b * 288 + ii) * 128 + row]);
  }
  float L = 0.f;
  float o[16];
  #pragma unroll
  for (int e = 0; e < 16; ++e) o[e] = 0.f;
  for (int cc = 0; cc < nc; ++cc){
    int ii = (cc < nheavy) ? cc * (61 - 4 * cc) + t - (8 * cc + 7)
                           : 232 + t - (t >> 3);
    int id = b * 288 + ii;
    float mc = ML[id * 128 + row];
    float lc = ML[id * 128 + 64 + row];
    float w = __expf(mc - M) * lc;
    L += w;
    const short* op = Opart + (size_t)id * 8192 + row * 128 + cgp * 16;
    bf16x8 v0 = *(const bf16x8*)(op);
    bf16x8 v1 = *(const bf16x8*)(op + 8);
    #pragma unroll
    for (int e = 0; e < 8; ++e){
      o[e]     += w * bf2f(v0[e]);
      o[8 + e] += w * bf2f(v1[e]);
    }
  }
  float inv = 1.f / L;
  float* dst = out + ((size_t)b * S_LEN + t * 64 + row) * HEAD + cgp * 16;
  #pragma unroll
  for (int e4 = 0; e4 < 4; ++e4){
    float4 w4 = { o[e4*4]*inv, o[e4*4+1]*inv, o[e4*4+2]*inv, o[e4*4+3]*inv };
    *(float4*)(dst + e4 * 4) = w4;
  }
}

// ---------------------------------------------------------------------------
extern "C" void kernel_launch(void* const* d_in, const int* in_sizes, int n_in,
                              void* d_out, int out_size, void* d_ws, size_t ws_size,
                              hipStream_t stream){
  const float* x  = (const float*)d_in[0];
  const float* Wq = (const float*)d_in[1];
  const float* bq = (const float*)d_in[2];
  const float* Wk = (const float*)d_in[3];
  const float* bk = (const float*)d_in[4];
  const float* Wv = (const float*)d_in[5];
  const float* bv = (const float*)d_in[6];
  float* out = (float*)d_out;

  char* ws = (char*)d_ws;
  short* WT    = (short*)(ws);                         // 768 KB
  float* bias  = (float*)(ws + 786432);                // 1.5 KB
  short* Qb    = (short*)(ws + (1u << 20));            // 4 MB
  short* Kb    = (short*)(ws + (1u << 20) + 4194304u); // 4 MB
  short* VTb   = (short*)(ws + (1u << 20) + 8388608u); // 4 MB
  short* Opart = (short*)(ws + 13631488u);             // 1152*16KB = 18.9 MB
  float* ML    = (float*)(ws + 32505856u);             // 576 KB

  prep_w<<<1536, 256, 0, stream>>>(Wq, bq, Wk, bk, Wv, bv, WT, bias);
  qkv_proj<<<256, 512, 0, stream>>>(x, WT, bias, Qb, Kb, VTb);
  attn<<<dim3(4, 288), 256, 0, stream>>>(Qb, Kb, VTb, Opart, ML);
  combine<<<dim3(64, 4), 512, 0, stream>>>(Opart, ML, out);
}